// Round 6
// baseline (336.054 us; speedup 1.0000x reference)
//
#include <hip/hip_runtime.h>

#define TT 1024
#define NB 4096
#define HH 50
#define DTC 0.1f
#define NL2E2 -2.8853900817779268f   // -2*log2(e)
#define RSTRIDE 68                   // ushorts/col: 34 dwords -> conflict-free b64 reads
#define CPB 8                        // real columns per block (2 blocks/CU for TLP)

typedef __attribute__((ext_vector_type(8))) short short8;
typedef __attribute__((ext_vector_type(4))) short short4v;
typedef __attribute__((ext_vector_type(4))) float float4v;
typedef __attribute__((ext_vector_type(2))) unsigned int uint2v;

__device__ __forceinline__ unsigned short f2bf(float f) {
    unsigned int u = __builtin_bit_cast(unsigned int, f);
    u += 0x7FFFu + ((u >> 16) & 1u);   // RNE
    return (unsigned short)(u >> 16);
}

// LDS-only barrier: leave global loads/stores in flight (no vmcnt drain).
#define BAR() __asm__ volatile("s_waitcnt lgkmcnt(0)\n\ts_barrier" ::: "memory")

// A_aug 64x64 bf16: rows 0..49 cols 0..49 = 0.2*Jrec; row 50 cols 0..49 = 0.2*Jout@Jrec;
// everything else 0.  Per-row vectors (fp32): jinv = 0.1*Jin (row50: 0.1*Jout@Jin),
// biasv = 0.1*bias (row50: 0.1*Jout@bias).  Update:
//   h_next = A_aug @ sigmoid(2h) + [0.9*h + jinv*x_t + biasv]   (C operand)
// Row 50 then carries out_t exactly.
__global__ void setup_kernel(const float* __restrict__ Jin,
                             const float* __restrict__ Jrec,
                             const float* __restrict__ Jout,
                             const float* __restrict__ bias,
                             const float* __restrict__ h0,
                             float* __restrict__ out0,
                             float* __restrict__ jinv,
                             float* __restrict__ biasv,
                             unsigned short* __restrict__ Aaug) {
    const int tid = threadIdx.x;
    const int blk = blockIdx.x;
    if (blk < 16) {
        const int col = blk * 256 + tid;
        float s = 0.f;
        for (int i = 0; i < HH; ++i) s += Jout[i] * h0[i * NB + col];
        out0[col] = s;
    } else {
        for (int idx = tid; idx < 64 * 64; idx += 256) {
            const int row = idx >> 6, k = idx & 63;
            float v = 0.f;
            if (row < HH && k < HH) v = 2.0f * DTC * Jrec[row * HH + k];
            else if (row == HH && k < HH) {
                float s = 0.f;
                for (int i = 0; i < HH; ++i) s += Jout[i] * Jrec[i * HH + k];
                v = 2.0f * DTC * s;
            }
            Aaug[idx] = f2bf(v);
        }
        if (tid < 64) {
            float ji = 0.f, bi = 0.f;
            if (tid < HH) { ji = DTC * Jin[tid]; bi = DTC * bias[tid]; }
            else if (tid == HH) {
                float sj = 0.f, sb = 0.f;
                for (int i = 0; i < HH; ++i) { sj += Jout[i] * Jin[i]; sb += Jout[i] * bias[i]; }
                ji = DTC * sj; bi = DTC * sb;
            }
            jinv[tid] = ji; biasv[tid] = bi;
        }
    }
}

// 512 blocks x 256 threads; wave w = rows 16w..16w+15; block = 8 real batch cols
// (lanes n>=8 duplicate column n-8 -> 2 independent blocks/CU for latency hiding).
// h in fp32 C-layout regs (row = 16w+4q+reg, col). Row 50 carries out_t.
// Global I/O batched per 8 steps; inner loop: LDS + MFMA + VALU only.
__global__ void __launch_bounds__(256, 2) rnn_kernel(
        const float* __restrict__ x,
        const float* __restrict__ h0,
        const float* __restrict__ out0,
        const float* __restrict__ jinv,
        const float* __restrict__ biasv,
        const unsigned short* __restrict__ Aaug,
        float* __restrict__ out) {
    __shared__ unsigned short rbuf[2][16][RSTRIDE];

    const int tid  = threadIdx.x;
    const int w    = tid >> 6;
    const int lane = tid & 63;
    const int n    = lane & 15;
    const int q    = lane >> 4;
    const int col  = blockIdx.x * CPB + (n & (CPB - 1));   // duplicated for n>=8
    const bool real = (n < CPB);
    const int row0 = 16 * w + 4 * q;

    // A fragments, contiguous our-k (slot permutation cancels between A and B frags)
    short8 a0, a1;
    {
        const unsigned short* ap = Aaug + ((16 * w + n) << 6) + (q << 3);
        a0 = *(const short8*)ap;
        a1 = *(const short8*)(ap + 32);
    }

    float ji[4], bi[4], h[4];
#pragma unroll
    for (int r = 0; r < 4; ++r) {
        ji[r] = jinv[row0 + r];
        bi[r] = biasv[row0 + r];
        h[r] = (row0 + r < HH) ? h0[(row0 + r) * NB + col] : 0.f;
    }
    const bool outlane = (w == 3) && (q == 0);   // holds row 50 in h[2]
    if (outlane) h[2] = out0[col];

    const float* xp = x + col;
    float* outp = out + col;

    // initial r'(h0) into buffer 0
    {
        unsigned int u[4];
#pragma unroll
        for (int r = 0; r < 4; ++r) {
            float e = __builtin_amdgcn_exp2f(NL2E2 * h[r]);
            float rv = __builtin_amdgcn_rcpf(1.0f + e);
            u[r] = __builtin_bit_cast(unsigned int, rv) + 0x8000u;
        }
        uint2v pk;
        pk[0] = __builtin_amdgcn_perm(u[1], u[0], 0x07060302u);
        pk[1] = __builtin_amdgcn_perm(u[3], u[2], 0x07060302u);
        *(uint2v*)&rbuf[0][n][row0] = pk;
    }

    unsigned short* const wr0 = &rbuf[0][n][row0];
    unsigned short* const wr1 = &rbuf[1][n][row0];
    const unsigned short* const rd0 = &rbuf[0][n][q << 3];
    const unsigned short* const rd1 = &rbuf[1][n][q << 3];

    // x batch for group 0
    float xs[8], xt[8], ob[8];
#pragma unroll
    for (int i = 0; i < 8; ++i) xs[i] = xp[i * NB];

    __syncthreads();   // one-time full sync

    for (int g = 0; g < TT / 8; ++g) {
        // prefetch next group's x (waited next group -> off the chain)
        const int base = (g + 1) * 8;
#pragma unroll
        for (int i = 0; i < 8; ++i) {
            const int idx = (base + i < TT) ? base + i : TT - 1;
            xt[i] = xp[idx * NB];
        }

#pragma unroll
        for (int i = 0; i < 8; ++i) {
            // B-frags for this step (written by all waves pre-barrier)
            const unsigned short* rp = (i & 1) ? rd1 : rd0;
            short4v b0a = *(const short4v*)(rp);
            short4v b0b = *(const short4v*)(rp + 4);
            short4v b1a = *(const short4v*)(rp + 32);
            short4v b1b = *(const short4v*)(rp + 36);
            short8 b0 = __builtin_shufflevector(b0a, b0b, 0, 1, 2, 3, 4, 5, 6, 7);
            short8 b1 = __builtin_shufflevector(b1a, b1b, 0, 1, 2, 3, 4, 5, 6, 7);

            // C operand: 0.9*h + jin*x_t + bias  (independent of the LDS read)
            float4v c;
#pragma unroll
            for (int r = 0; r < 4; ++r)
                c[r] = __builtin_fmaf(h[r], 1.0f - DTC,
                                      __builtin_fmaf(ji[r], xs[i], bi[r]));

            c = __builtin_amdgcn_mfma_f32_16x16x32_bf16(a0, b0, c, 0, 0, 0);
            c = __builtin_amdgcn_mfma_f32_16x16x32_bf16(a1, b1, c, 0, 0, 0);
#pragma unroll
            for (int r = 0; r < 4; ++r) h[r] = c[r];

            ob[i] = h[2];   // row 50 = out_t (meaningful in outlanes only)

            // r' = sigmoid(2h) -> bf16 pack -> exchange
            unsigned int u[4];
#pragma unroll
            for (int r = 0; r < 4; ++r) {
                float e = __builtin_amdgcn_exp2f(NL2E2 * h[r]);
                float rv = __builtin_amdgcn_rcpf(1.0f + e);
                u[r] = __builtin_bit_cast(unsigned int, rv) + 0x8000u;
            }
            uint2v pk;
            pk[0] = __builtin_amdgcn_perm(u[1], u[0], 0x07060302u);
            pk[1] = __builtin_amdgcn_perm(u[3], u[2], 0x07060302u);
            *(uint2v*)((i & 1) ? wr0 : wr1) = pk;

            BAR();
        }

        // batched out stores (fire-and-forget) + x rotate
        if (outlane && real) {
            const int tb = g * 8;
#pragma unroll
            for (int i = 0; i < 8; ++i) outp[(tb + i) * NB] = ob[i];
        }
#pragma unroll
        for (int i = 0; i < 8; ++i) xs[i] = xt[i];
    }
}

extern "C" void kernel_launch(void* const* d_in, const int* in_sizes, int n_in,
                              void* d_out, int out_size, void* d_ws, size_t ws_size,
                              hipStream_t stream) {
    (void)in_sizes; (void)n_in; (void)out_size; (void)ws_size;
    const float* x    = (const float*)d_in[0];
    const float* Jin  = (const float*)d_in[1];
    const float* Jrec = (const float*)d_in[2];
    const float* Jout = (const float*)d_in[3];
    const float* bias = (const float*)d_in[4];
    const float* h0   = (const float*)d_in[5];
    float* out = (float*)d_out;

    float* ws_out0 = (float*)d_ws;                            // 4096 f32
    float* ws_jin  = ws_out0 + NB;                            // 64 f32
    float* ws_bias = ws_jin + 64;                             // 64 f32
    unsigned short* ws_A = (unsigned short*)(ws_bias + 64);   // 4096 bf16

    hipLaunchKernelGGL(setup_kernel, dim3(17), dim3(256), 0, stream,
                       Jin, Jrec, Jout, bias, h0, ws_out0, ws_jin, ws_bias, ws_A);
    hipLaunchKernelGGL(rnn_kernel, dim3(NB / CPB), dim3(256), 0, stream,
                       x, h0, ws_out0, ws_jin, ws_bias, ws_A, out);
}